// Round 3
// baseline (14570.006 us; speedup 1.0000x reference)
//
#include <hip/hip_runtime.h>
#include <cmath>

// Problem dims (fixed at compile time)
constexpr int Bv  = 64;
constexpr int T   = 512;
constexpr int H   = 512;   // h_third
constexpr int OUTD = 256;
constexpr int M   = Bv * T;  // 32768 rows for the big GEMMs

// ---------------------------------------------------------------------------
// GEMM: C[M,N] = act(A[M,512] @ W[512,N] + b1[N] (+ b2[N]))   (fp32, K=512)
// 64x64 tile, 256 threads, 4x4 microtile per thread.
// ---------------------------------------------------------------------------
__global__ __launch_bounds__(256) void gemm_bias_act(
    const float* __restrict__ A, const float* __restrict__ W,
    const float* __restrict__ b1, const float* __restrict__ b2,
    float* __restrict__ C, int N, int do_tanh)
{
    constexpr int K = 512;
    __shared__ float As[16][64];   // [k][m] (transposed on store)
    __shared__ float Bs[16][64];   // [k][n]

    const int tid  = threadIdx.x;
    const int row0 = blockIdx.x * 64;
    const int col0 = blockIdx.y * 64;
    const int tx = tid & 15, ty = tid >> 4;
    const int la_m = tid >> 2, la_k = (tid & 3) * 4;
    const int lb_k = tid >> 4, lb_n = (tid & 15) * 4;

    float acc[4][4] = {};

    const float* Aptr = A + (size_t)(row0 + la_m) * K + la_k;
    const float* Wptr = W + (size_t)lb_k * N + col0 + lb_n;

    for (int k0 = 0; k0 < K; k0 += 16) {
        const float4 a4 = *(const float4*)(Aptr + k0);
        const float4 b4 = *(const float4*)(Wptr + (size_t)k0 * N);
        As[la_k + 0][la_m] = a4.x;
        As[la_k + 1][la_m] = a4.y;
        As[la_k + 2][la_m] = a4.z;
        As[la_k + 3][la_m] = a4.w;
        *(float4*)&Bs[lb_k][lb_n] = b4;
        __syncthreads();
        #pragma unroll
        for (int k = 0; k < 16; ++k) {
            const float4 av = *(const float4*)&As[k][ty * 4];
            const float4 bv = *(const float4*)&Bs[k][tx * 4];
            acc[0][0] = fmaf(av.x, bv.x, acc[0][0]);
            acc[0][1] = fmaf(av.x, bv.y, acc[0][1]);
            acc[0][2] = fmaf(av.x, bv.z, acc[0][2]);
            acc[0][3] = fmaf(av.x, bv.w, acc[0][3]);
            acc[1][0] = fmaf(av.y, bv.x, acc[1][0]);
            acc[1][1] = fmaf(av.y, bv.y, acc[1][1]);
            acc[1][2] = fmaf(av.y, bv.z, acc[1][2]);
            acc[1][3] = fmaf(av.y, bv.w, acc[1][3]);
            acc[2][0] = fmaf(av.z, bv.x, acc[2][0]);
            acc[2][1] = fmaf(av.z, bv.y, acc[2][1]);
            acc[2][2] = fmaf(av.z, bv.z, acc[2][2]);
            acc[2][3] = fmaf(av.z, bv.w, acc[2][3]);
            acc[3][0] = fmaf(av.w, bv.x, acc[3][0]);
            acc[3][1] = fmaf(av.w, bv.y, acc[3][1]);
            acc[3][2] = fmaf(av.w, bv.z, acc[3][2]);
            acc[3][3] = fmaf(av.w, bv.w, acc[3][3]);
        }
        __syncthreads();
    }

    float4 bias = *(const float4*)&b1[col0 + tx * 4];
    if (b2 != nullptr) {
        const float4 e = *(const float4*)&b2[col0 + tx * 4];
        bias.x += e.x; bias.y += e.y; bias.z += e.z; bias.w += e.w;
    }
    #pragma unroll
    for (int i = 0; i < 4; ++i) {
        float4 v;
        v.x = acc[i][0] + bias.x;
        v.y = acc[i][1] + bias.y;
        v.z = acc[i][2] + bias.z;
        v.w = acc[i][3] + bias.w;
        if (do_tanh) {
            v.x = tanhf(v.x); v.y = tanhf(v.y); v.z = tanhf(v.z); v.w = tanhf(v.w);
        }
        *(float4*)&C[(size_t)(row0 + ty * 4 + i) * N + col0 + tx * 4] = v;
    }
}

// ---------------------------------------------------------------------------
// hs linear scan, in place: buf holds tanh(x@Ws+bs) on entry, hs on exit.
// ---------------------------------------------------------------------------
__global__ __launch_bounds__(256) void scan_hs_kernel(
    float* __restrict__ buf, const float* __restrict__ tau)
{
    const int h  = blockIdx.x * 256 + threadIdx.x;
    const int b0 = blockIdx.y * 4;
    const float inv = 1.0f / tau[h];
    const float am  = 1.0f - inv;
    float s0 = 0.f, s1 = 0.f, s2 = 0.f, s3 = 0.f;
    const size_t bs_ = (size_t)T * H;
    const size_t i0 = (size_t)b0 * bs_ + h;
    for (int t = 0; t < T; ++t) {
        const size_t o = i0 + (size_t)t * H;
        const float x0 = buf[o];
        const float x1 = buf[o + bs_];
        const float x2 = buf[o + 2 * bs_];
        const float x3 = buf[o + 3 * bs_];
        s0 = am * s0 + inv * x0;
        s1 = am * s1 + inv * x1;
        s2 = am * s2 + inv * x2;
        s3 = am * s3 + inv * x3;
        buf[o]           = s0;
        buf[o + bs_]     = s1;
        buf[o + 2 * bs_] = s2;
        buf[o + 3 * bs_] = s3;
    }
}

// ---------------------------------------------------------------------------
// zero the cross-block progress flags (d_out scratch region)
// ---------------------------------------------------------------------------
__global__ void zero_flags_kernel(int* __restrict__ prog)
{
    prog[threadIdx.x] = 0;
}

// ---------------------------------------------------------------------------
// Nonlinear recurrence, weight-in-registers, 4 blocks per batch row.
//   h_t = (1-inv)*h_{t-1} + inv * tanh( U[b,t,:] + h_{t-1} @ Wr )
// Grid = 256 blocks (1 per CU, all co-resident). Block (r,p): batch row r,
// cols [128p,128p+128). 512 threads: cg = tid&31 -> 4 cols, s = tid>>5 ->
// k-slice [32s,32s+32). Each thread holds its 32x4 weight slab in 128 VGPRs.
// Cross-block state exchange per step via agent-scope release/acquire flags.
// ---------------------------------------------------------------------------
__global__ __launch_bounds__(512, 2) void recur_kernel(
    const float* __restrict__ U, float* __restrict__ Hout,
    const float* __restrict__ Wr, const float* __restrict__ tau,
    int* __restrict__ prog)
{
    __shared__ float h_lds[H];          // full previous state h_{t-1}
    __shared__ float accb[16][128];     // partials: [k-slice][local col]

    const int tid = threadIdx.x;
    const int bid = blockIdx.x;
    // Swizzle so the 4 blocks of a row land on the same XCD (if bid%8 = XCD):
    const int x = bid & 7, q = bid >> 3;
    const int r = (q >> 2) * 8 + x;     // batch row 0..63
    const int p = q & 3;                // column quarter 0..3
    const int p128 = p * 128;

    const int cg = tid & 31;            // col group: cols 4cg..4cg+3 (local)
    const int s  = tid >> 5;            // k-slice: [32s, 32s+32)
    const int k0 = s * 32;
    const int j0 = p128 + cg * 4;       // global col of this thread's 4 cols

    // ---- load this thread's 32x4 weight slab into registers (one time) ----
    float4 w[32];
    #pragma unroll
    for (int i = 0; i < 32; ++i)
        w[i] = *(const float4*)&Wr[(size_t)(k0 + i) * H + j0];

    // ---- per-owner state (threads 0..127 own column p128+tid) ----
    float inv = 0.f, am = 0.f, h_reg = 0.f;
    const float* Urow = nullptr;
    float*       Hrow = nullptr;
    if (tid < 128) {
        inv = 1.0f / tau[p128 + tid];
        am  = 1.0f - inv;
        Urow = U    + (size_t)r * T * H + p128 + tid;
        Hrow = Hout + (size_t)r * T * H + p128 + tid;
    }
    const float* Hall = Hout + (size_t)r * T * H;   // full row, for gather
    const int fbase = r * 4;

    h_lds[tid] = 0.0f;
    __syncthreads();

    for (int t = 0; t < T; ++t) {
        const float uval = (tid < 128) ? Urow[(size_t)t * H] : 0.0f;

        // ---- phase 1: partial matvec from registers ----
        float4 acc = make_float4(0.f, 0.f, 0.f, 0.f);
        #pragma unroll
        for (int i = 0; i < 8; ++i) {
            const float4 h4 = *(const float4*)&h_lds[k0 + 4 * i];
            acc.x = fmaf(h4.x, w[4*i+0].x, acc.x);
            acc.y = fmaf(h4.x, w[4*i+0].y, acc.y);
            acc.z = fmaf(h4.x, w[4*i+0].z, acc.z);
            acc.w = fmaf(h4.x, w[4*i+0].w, acc.w);
            acc.x = fmaf(h4.y, w[4*i+1].x, acc.x);
            acc.y = fmaf(h4.y, w[4*i+1].y, acc.y);
            acc.z = fmaf(h4.y, w[4*i+1].z, acc.z);
            acc.w = fmaf(h4.y, w[4*i+1].w, acc.w);
            acc.x = fmaf(h4.z, w[4*i+2].x, acc.x);
            acc.y = fmaf(h4.z, w[4*i+2].y, acc.y);
            acc.z = fmaf(h4.z, w[4*i+2].z, acc.z);
            acc.w = fmaf(h4.z, w[4*i+2].w, acc.w);
            acc.x = fmaf(h4.w, w[4*i+3].x, acc.x);
            acc.y = fmaf(h4.w, w[4*i+3].y, acc.y);
            acc.z = fmaf(h4.w, w[4*i+3].z, acc.z);
            acc.w = fmaf(h4.w, w[4*i+3].w, acc.w);
        }
        *(float4*)&accb[s][cg * 4] = acc;
        __syncthreads();

        // ---- phase 2: reduce + state update (owners = threads 0..127) ----
        if (tid < 128) {
            float red = 0.f;
            #pragma unroll
            for (int ss = 0; ss < 16; ++ss) red += accb[ss][tid];
            const float a = red + uval;
            const float hnew = am * h_reg + inv * tanhf(a);
            h_reg = hnew;
            Hrow[(size_t)t * H] = hnew;       // publish shard
            h_lds[p128 + tid] = hnew;         // own part of h_t
            __threadfence();                  // make shard agent-visible
        }
        __syncthreads();                      // all owner fences done

        if (t + 1 < T) {
            // ---- post own flag, then spin for the 3 remote quarters ----
            if (tid == 0)
                __hip_atomic_store(&prog[fbase + p], t + 1,
                                   __ATOMIC_RELEASE, __HIP_MEMORY_SCOPE_AGENT);
            if (tid >= 1 && tid <= 3) {
                const int rq = (p + tid) & 3;
                while (__hip_atomic_load(&prog[fbase + rq],
                                         __ATOMIC_ACQUIRE, __HIP_MEMORY_SCOPE_AGENT) < t + 1) {}
            }
            __syncthreads();

            // ---- gather remote 384 state values into h_lds ----
            if (tid >= 128) {
                const int e = (p128 + tid) & 511;   // offsets past own shard
                h_lds[e] = Hall[(size_t)t * H + e];
            }
            __syncthreads();
        }
    }
}

// ---------------------------------------------------------------------------
extern "C" void kernel_launch(void* const* d_in, const int* in_sizes, int n_in,
                              void* d_out, int out_size, void* d_ws, size_t ws_size,
                              hipStream_t stream)
{
    const float* x     = (const float*)d_in[0];
    const float* Ws    = (const float*)d_in[1];
    const float* bs    = (const float*)d_in[2];
    const float* Wi    = (const float*)d_in[3];
    const float* bi    = (const float*)d_in[4];
    const float* Wc    = (const float*)d_in[5];
    const float* bc    = (const float*)d_in[6];
    const float* Wm    = (const float*)d_in[7];
    const float* bm    = (const float*)d_in[8];
    const float* Wir   = (const float*)d_in[9];
    const float* bir   = (const float*)d_in[10];
    const float* Wcr   = (const float*)d_in[11];
    const float* bcr   = (const float*)d_in[12];
    const float* tau_s = (const float*)d_in[13];
    const float* tau_i = (const float*)d_in[14];
    const float* tau_c = (const float*)d_in[15];
    float* out = (float*)d_out;

    float* bufA = (float*)d_ws;                 // [B,T,H]  64 MB
    float* bufB = bufA + (size_t)M * H;         // [B,T,H]  64 MB
    // progress flags live in d_out (pure scratch until final GEMM overwrites):
    // recur1 uses prog[0..255], recur2 uses prog[256..511].
    int* prog = (int*)d_out;

    const dim3 blk(256);

    zero_flags_kernel<<<1, 512, 0, stream>>>(prog);

    // 1) bufA = tanh(x @ Ws + bs)
    gemm_bias_act<<<dim3(M / 64, H / 64), blk, 0, stream>>>(x, Ws, bs, nullptr, bufA, H, 1);
    // 2) bufA = linear scan -> hs_all
    scan_hs_kernel<<<dim3(H / 256, Bv / 4), blk, 0, stream>>>(bufA, tau_s);
    // 3) bufB = hs_all @ Wi + (bi + bir)
    gemm_bias_act<<<dim3(M / 64, H / 64), blk, 0, stream>>>(bufA, Wi, bi, bir, bufB, H, 0);
    // 4) bufA = hi_all  (weight-in-register recurrence, 4 blocks/row)
    recur_kernel<<<dim3(256), dim3(512), 0, stream>>>(bufB, bufA, Wir, tau_i, prog);
    // 5) bufB = hi_all @ Wc + (bc + bcr)
    gemm_bias_act<<<dim3(M / 64, H / 64), blk, 0, stream>>>(bufA, Wc, bc, bcr, bufB, H, 0);
    // 6) bufA = hc_all
    recur_kernel<<<dim3(256), dim3(512), 0, stream>>>(bufB, bufA, Wcr, tau_c, prog + 256);
    // 7) out = hc_all @ Wm + bm
    gemm_bias_act<<<dim3(M / 64, OUTD / 64), blk, 0, stream>>>(bufA, Wm, bm, nullptr, out, OUTD, 0);
}